// Round 3
// baseline (84.025 us; speedup 1.0000x reference)
//
#include <hip/hip_runtime.h>

// QuantumNAT: 4-qubit, 3-layer circuit. Reduction:
//   <Z_q> = Tr[ (W^dag Z_q W) * (rho_0 x rho_1 x rho_2 x rho_3) ]
// with rho_i = (I - sin(x_i) Y + cos(x_i) Z)/2  (RX(x)|0> has no X component).
// => <Z_q> = sum over 81 Pauli strings {I,Y,Z}^4 of coef_q[P] * prod_i m_i(P_i),
// m(I)=1, m(Y)=-sin(x_i), m(Z)=cos(x_i). coef depends only on weights.
//
// R3: barrier-light prep. Wave 0 evolves the 16x16 unitary W entirely in
// registers (one column per lane, gates unrolled, CNOT perms = compile-time
// register renames), gate 2x2s broadcast via __shfl. 3 barriers total
// (was 30). Coef table padded to [4][9][12] so the multilinear inner loop
// loads coefs as ds_read_b128 pairs.

#define NQ 4
#define NLAYERS 3
#define DIM 16
#define NPAULI 81
#define SPT 4
#define BLOCK 256

__device__ __forceinline__ float2 cmul(float2 a, float2 b) {
    return make_float2(a.x * b.x - a.y * b.y, a.x * b.y + a.y * b.x);
}
__device__ __forceinline__ float2 cadd(float2 a, float2 b) {
    return make_float2(a.x + b.x, a.y + b.y);
}

__global__ __launch_bounds__(256) void qnat_fused(const float4* __restrict__ x4,
                                                  const float* __restrict__ w,
                                                  float4* __restrict__ out4,
                                                  int B) {
    __shared__ __align__(16) float2 Wl[DIM][DIM];      // W[row][col]
    __shared__ __align__(16) float2 A[NQ][DIM][DIM];   // A_q = W^dag Z_q W
    __shared__ __align__(16) float  Cs[NQ][9][12];     // padded Pauli coefs
    const int tid = threadIdx.x;

    // ---------------- wave-0 prep: W in registers, no internal barriers ----
    if (tid < 64) {
        // each of lanes 0..11 computes one fused gate U = RZ(w2)@RY(w1)@RX(w0)
        float2 u00, u01, u10, u11;
        {
            int g = (tid < NLAYERS * NQ) ? tid : 0;
            float th0 = w[g * 3 + 0], th1 = w[g * 3 + 1], th2 = w[g * 3 + 2];
            float sx, cx; __sincosf(0.5f * th0, &sx, &cx);
            float sy, cy; __sincosf(0.5f * th1, &sy, &cy);
            float sz, cz; __sincosf(0.5f * th2, &sz, &cz);
            // M = RY @ RX
            float2 M00 = make_float2(cy * cx,  sy * sx);
            float2 M01 = make_float2(-sy * cx, -cy * sx);
            float2 M10 = make_float2(sy * cx,  -cy * sx);
            float2 M11 = make_float2(cy * cx,  -sy * sx);
            float2 e0 = make_float2(cz, -sz), e1 = make_float2(cz, sz);
            u00 = cmul(e0, M00); u01 = cmul(e0, M01);
            u10 = cmul(e1, M10); u11 = cmul(e1, M11);
        }
        // lane c (<16) owns column c of W; evolve in registers
        const int c = tid & 15;
        float2 wc[16];
#pragma unroll
        for (int r = 0; r < 16; ++r) wc[r] = make_float2(r == c ? 1.f : 0.f, 0.f);
#pragma unroll
        for (int layer = 0; layer < NLAYERS; ++layer) {
#pragma unroll
            for (int i = 0; i < NQ; ++i) {
                const int g = layer * NQ + i;
                float2 g00 = make_float2(__shfl(u00.x, g), __shfl(u00.y, g));
                float2 g01 = make_float2(__shfl(u01.x, g), __shfl(u01.y, g));
                float2 g10 = make_float2(__shfl(u10.x, g), __shfl(u10.y, g));
                float2 g11 = make_float2(__shfl(u11.x, g), __shfl(u11.y, g));
                const int pos = 3 - i;  // qubit i bit position (qubit 0 = MSB)
#pragma unroll
                for (int h = 0; h < 8; ++h) {
                    const int low = h & ((1 << pos) - 1);
                    const int r0 = ((h >> pos) << (pos + 1)) | low;
                    const int r1 = r0 | (1 << pos);
                    float2 a = wc[r0], b = wc[r1];
                    wc[r0] = cadd(cmul(g00, a), cmul(g01, b));
                    wc[r1] = cadd(cmul(g10, a), cmul(g11, b));
                }
            }
            // CNOT chain (0->1),(1->2),(2->3): W'[r] = W[s01(s12(s23(r)))]
            float2 nw[16];
#pragma unroll
            for (int r = 0; r < 16; ++r) {
                int x = r;
                if (x & 2) x ^= 1;   // s23
                if (x & 4) x ^= 2;   // s12
                if (x & 8) x ^= 4;   // s01
                nw[r] = wc[x];
            }
#pragma unroll
            for (int r = 0; r < 16; ++r) wc[r] = nw[r];
        }
        if (tid < 16) {
#pragma unroll
            for (int r = 0; r < 16; ++r) Wl[r][c] = wc[r];
        }
    }

    // ---------------- all threads: per-sample moment products --------------
    const int base = blockIdx.x * (BLOCK * SPT) + tid;
    float t01[SPT][9], t23[SPT][9];
#pragma unroll
    for (int k = 0; k < SPT; ++k) {
        int s = base + k * BLOCK;
        float4 xv = (s < B) ? x4[s] : make_float4(0.f, 0.f, 0.f, 0.f);
        float s0, c0; __sincosf(xv.x, &s0, &c0);
        float s1, c1; __sincosf(xv.y, &s1, &c1);
        float s2, c2; __sincosf(xv.z, &s2, &c2);
        float s3, c3; __sincosf(xv.w, &s3, &c3);
        float m0[3] = { 1.f, -s0, c0 }, m1[3] = { 1.f, -s1, c1 };
        float m2[3] = { 1.f, -s2, c2 }, m3[3] = { 1.f, -s3, c3 };
#pragma unroll
        for (int a = 0; a < 3; ++a)
#pragma unroll
            for (int b = 0; b < 3; ++b) {
                t01[k][a * 3 + b] = m0[a] * m1[b];
                t23[k][a * 3 + b] = m2[a] * m3[b];
            }
    }

    __syncthreads();  // Wl ready

    // ---------------- A_q[j][k] = sum_b conj(W[b][j]) * z_q(b) * W[b][k] ---
    for (int task = tid; task < NQ * DIM * DIM; task += BLOCK) {
        int q = task >> 8, j = (task >> 4) & 15, k = task & 15;
        int pos = 3 - q;
        float2 acc = make_float2(0.f, 0.f);
        for (int b = 0; b < DIM; ++b) {
            float z = ((b >> pos) & 1) ? -1.f : 1.f;
            float2 wj = Wl[b][j], wk = Wl[b][k];
            acc.x += z * (wj.x * wk.x + wj.y * wk.y);
            acc.y += z * (wj.x * wk.y - wj.y * wk.x);
        }
        A[q][j][k] = acc;
    }
    __syncthreads();

    // ---------------- Cs[q][a][b] = Re(Tr[A_q * Pauli(P=a*9+b)]) / 16 ------
    // digit encoding per qubit: 0=I, 1=Y, 2=Z; P = ((p0*3+p1)*3+p2)*3+p3
    for (int task = tid; task < NQ * NPAULI; task += BLOCK) {
        int q = task / NPAULI, P = task % NPAULI;
        int p0 = P / 27, p1 = (P / 9) % 3, p2 = (P / 3) % 3, p3 = P % 3;
        int p[4] = { p0, p1, p2, p3 };
        int flip = 0;
        for (int i = 0; i < 4; ++i)
            if (p[i] == 1) flip |= 1 << (3 - i);
        float accr = 0.f;
        for (int j = 0; j < DIM; ++j) {
            int k = j ^ flip;
            int ny = 0; float sgn = 1.f;
            for (int i = 0; i < 4; ++i) {
                int ji = (j >> (3 - i)) & 1;
                if (p[i] != 0 && ji) sgn = -sgn;
                if (p[i] == 1) ny++;
            }
            float phr, phi;
            switch (ny & 3) {
                case 0:  phr = sgn;  phi = 0.f;  break;
                case 1:  phr = 0.f;  phi = sgn;  break;
                case 2:  phr = -sgn; phi = 0.f;  break;
                default: phr = 0.f;  phi = -sgn; break;
            }
            float2 a = A[q][j][k];
            accr += a.x * phr - a.y * phi;   // result is real (A Hermitian)
        }
        Cs[q][P / 9][P % 9] = accr * (1.f / 16.f);
    }
    __syncthreads();

    // ---------------- main: 81-term multilinear form ------------------------
    float acc[SPT][4];
#pragma unroll
    for (int k = 0; k < SPT; ++k)
#pragma unroll
        for (int q = 0; q < 4; ++q) acc[k][q] = 0.f;

#pragma unroll
    for (int q = 0; q < 4; ++q) {
#pragma unroll
        for (int a = 0; a < 9; ++a) {
            const float4 cA = *(const float4*)&Cs[q][a][0];  // ds_read_b128
            const float4 cB = *(const float4*)&Cs[q][a][4];  // ds_read_b128
            const float  c8 = Cs[q][a][8];
#pragma unroll
            for (int k = 0; k < SPT; ++k) {
                float inner = 0.f;
                inner = fmaf(cA.x, t23[k][0], inner);
                inner = fmaf(cA.y, t23[k][1], inner);
                inner = fmaf(cA.z, t23[k][2], inner);
                inner = fmaf(cA.w, t23[k][3], inner);
                inner = fmaf(cB.x, t23[k][4], inner);
                inner = fmaf(cB.y, t23[k][5], inner);
                inner = fmaf(cB.z, t23[k][6], inner);
                inner = fmaf(cB.w, t23[k][7], inner);
                inner = fmaf(c8,   t23[k][8], inner);
                acc[k][q] = fmaf(t01[k][a], inner, acc[k][q]);
            }
        }
    }

#pragma unroll
    for (int k = 0; k < SPT; ++k) {
        int s = base + k * BLOCK;
        if (s < B)
            out4[s] = make_float4(acc[k][0], acc[k][1], acc[k][2], acc[k][3]);
    }
}

extern "C" void kernel_launch(void* const* d_in, const int* in_sizes, int n_in,
                              void* d_out, int out_size, void* d_ws, size_t ws_size,
                              hipStream_t stream) {
    const float* x = (const float*)d_in[0];   // [B,4] fp32
    const float* w = (const float*)d_in[1];   // [3,4,3] fp32
    float* out = (float*)d_out;               // [B,4] fp32
    int B = in_sizes[0] / 4;

    int grid = (B + BLOCK * SPT - 1) / (BLOCK * SPT);
    qnat_fused<<<grid, BLOCK, 0, stream>>>((const float4*)x, w, (float4*)out, B);
}